// Round 7
// baseline (3028.114 us; speedup 1.0000x reference)
//
#include <hip/hip_runtime.h>

#define BB 64
#define SS 2048
#define DD 128
#define HH 128

typedef float v2f __attribute__((ext_vector_type(2)));

// packed dual-fp32 FMA: acc.{lo,hi} += a.{lo,hi} * b.{lo,hi}
#define PKFMA(acc, a, b) \
    asm("v_pk_fma_f32 %0, %1, %2, %0" : "+v"(acc) : "v"(a), "v"(b))

__device__ __forceinline__ float fast_tanh(float x) {
    // tanh(x) = 1 - 2/(e^{2x}+1); exact at +-inf, ~1e-6 rel err
    float e = __expf(2.0f * x);
    return 1.0f - __fdividef(2.0f, e + 1.0f);
}

// ---------------------------------------------------------------------------
// Kernel 1: xproj = x @ Wx + b  (register-tiled fp32 GEMM) — unchanged (~45us)
// ---------------------------------------------------------------------------
__global__ __launch_bounds__(256, 2)
void xproj_kernel(const float* __restrict__ x, const float* __restrict__ W,
                  const float* __restrict__ bias, float* __restrict__ out) {
    __shared__ __align__(16) float4 wxs[64 * 32];   // Wx half: [64 k][128 j]
    __shared__ __align__(16) float4 xsw[128 * 16];  // x half:  [128 r][64 k], swizzled
    const int tid = threadIdx.x;
    const int tx  = tid & 15;
    const int ty  = tid >> 4;
    const long row0 = (long)blockIdx.x * 128;

    float acc[8][8];
#pragma unroll
    for (int i = 0; i < 8; ++i)
#pragma unroll
        for (int j = 0; j < 8; ++j) acc[i][j] = 0.f;

    for (int kh = 0; kh < 2; ++kh) {
        {
            const float4* wg = (const float4*)(W + kh * 64 * HH);
#pragma unroll
            for (int i = 0; i < 8; ++i) wxs[tid + i * 256] = wg[tid + i * 256];
        }
        {
#pragma unroll
            for (int i = 0; i < 8; ++i) {
                const int g  = tid + i * 256;
                const int r  = g >> 4;
                const int k4 = g & 15;
                const float4 v = ((const float4*)(x + (row0 + r) * DD + kh * 64))[k4];
                xsw[r * 16 + (k4 ^ ((r >> 3) & 7))] = v;
            }
        }
        __syncthreads();

        for (int k4 = 0; k4 < 16; ++k4) {
            float4 xa[8];
#pragma unroll
            for (int i = 0; i < 8; ++i)
                xa[i] = xsw[(ty * 8 + i) * 16 + (k4 ^ (ty & 7))];
            float4 wa[4][2];
#pragma unroll
            for (int kk = 0; kk < 4; ++kk) {
                wa[kk][0] = wxs[(k4 * 4 + kk) * 32 + tx * 2];
                wa[kk][1] = wxs[(k4 * 4 + kk) * 32 + tx * 2 + 1];
            }
#pragma unroll
            for (int i = 0; i < 8; ++i) {
#pragma unroll
                for (int kk = 0; kk < 4; ++kk) {
                    const float xv = (kk == 0) ? xa[i].x : (kk == 1) ? xa[i].y
                                   : (kk == 2) ? xa[i].z : xa[i].w;
                    acc[i][0] = fmaf(xv, wa[kk][0].x, acc[i][0]);
                    acc[i][1] = fmaf(xv, wa[kk][0].y, acc[i][1]);
                    acc[i][2] = fmaf(xv, wa[kk][0].z, acc[i][2]);
                    acc[i][3] = fmaf(xv, wa[kk][0].w, acc[i][3]);
                    acc[i][4] = fmaf(xv, wa[kk][1].x, acc[i][4]);
                    acc[i][5] = fmaf(xv, wa[kk][1].y, acc[i][5]);
                    acc[i][6] = fmaf(xv, wa[kk][1].z, acc[i][6]);
                    acc[i][7] = fmaf(xv, wa[kk][1].w, acc[i][7]);
                }
            }
        }
        __syncthreads();
    }

    const float4 b0 = ((const float4*)bias)[tx * 2];
    const float4 b1 = ((const float4*)bias)[tx * 2 + 1];
#pragma unroll
    for (int i = 0; i < 8; ++i) {
        const float4 o0 = make_float4(acc[i][0] + b0.x, acc[i][1] + b0.y,
                                      acc[i][2] + b0.z, acc[i][3] + b0.w);
        const float4 o1 = make_float4(acc[i][4] + b1.x, acc[i][5] + b1.y,
                                      acc[i][6] + b1.z, acc[i][7] + b1.w);
        float4* og = (float4*)(out + (row0 + ty * 8 + i) * HH);
        og[tx * 2]     = o0;
        og[tx * 2 + 1] = o1;
    }
}

// ---------------------------------------------------------------------------
// Kernel 2: recurrence v6 — 64 blocks x ONE WAVE (64 threads). ZERO barriers.
//  Lane p owns cols (2p, 2p+1) with the FULL K=128 dot:
//   - Wh in 256 VGPRs (whA/whB, 64 v2f each), k-paired for v_pk_fma_f32
//   - h state in 1KB LDS, double-buffered; intra-wave visibility needs only
//     s_waitcnt lgkmcnt(0) (program-order DS per wave) — NO s_barrier
//   - no reduce (full-K per lane), tanh on all lanes
//   - h stored STRAIGHT to global each step; with no barrier there is no
//     vmcnt(0) drain anywhere, so stores are true fire-and-forget
//   - xp (xproj) for 16 steps in regs, prefetched one chunk ahead
// ---------------------------------------------------------------------------
__global__ __launch_bounds__(64, 1)
void rnn_kernel(const float* __restrict__ W, float* __restrict__ out) {
    const int CH = 16;
    const int NC = SS / CH;

    __shared__ __align__(16) float hb[2][HH];   // double-buffered h (1KB)

    const int b  = blockIdx.x;
    const int p  = threadIdx.x;   // 0..63
    const int c0 = 2 * p;         // cols (c0, c0+1)

    // Wh columns c0,c0+1 -> 256 VGPRs, paired along k for pk_fma:
    // whA[m] = (Wh[2m][c0],   Wh[2m+1][c0])
    // whB[m] = (Wh[2m][c0+1], Wh[2m+1][c0+1])
    v2f whA[64], whB[64];
#pragma unroll
    for (int m = 0; m < 64; ++m) {
        const v2f r0 = *(const v2f*)(W + (long)(DD + 2 * m) * HH + c0);
        const v2f r1 = *(const v2f*)(W + (long)(DD + 2 * m + 1) * HH + c0);
        v2f a; a.x = r0.x; a.y = r1.x; whA[m] = a;
        v2f q; q.x = r0.y; q.y = r1.y; whB[m] = q;
    }

    float* const xbase = out + (long)b * SS * HH;

    {
        v2f z; z.x = 0.f; z.y = 0.f;
        *(v2f*)&hb[0][c0] = z;
        *(v2f*)&hb[1][c0] = z;
    }

    // xp: xproj for this lane's cols, 16 steps per chunk, in registers
    v2f xp[16], nxt[16];
#pragma unroll
    for (int t = 0; t < 16; ++t)
        xp[t] = *(const v2f*)(xbase + (long)t * HH + c0);

    asm volatile("s_waitcnt lgkmcnt(0)" ::: "memory");  // hb init visible

    v2f hh; hh.x = 0.f; hh.y = 0.f;

    for (int c = 0; c < NC; ++c) {
        if (c + 1 < NC) {   // prefetch next chunk's xp (used 16 steps later)
#pragma unroll
            for (int t = 0; t < 16; ++t)
                nxt[t] = *(const v2f*)(xbase + (long)((c + 1) * CH + t) * HH + c0);
        }
#pragma unroll
        for (int tt = 0; tt < CH; ++tt) {
            const float4* hv = (const float4*)hb[(tt + 1) & 1];  // h_{t-1}
            v2f A0 = {0.f, 0.f}, A1 = {0.f, 0.f};
            v2f B0 = {0.f, 0.f}, B1 = {0.f, 0.f};
#pragma unroll
            for (int i = 0; i < 32; ++i) {
                const float4 h4 = hv[i];     // uniform address -> broadcast
                v2f hlo; hlo.x = h4.x; hlo.y = h4.y;
                v2f hhi; hhi.x = h4.z; hhi.y = h4.w;
                PKFMA(A0, hlo, whA[2 * i]);
                PKFMA(A1, hhi, whA[2 * i + 1]);
                PKFMA(B0, hlo, whB[2 * i]);
                PKFMA(B1, hhi, whB[2 * i + 1]);
            }
            const v2f SA = A0 + A1;          // v_pk_add
            const v2f SB = B0 + B1;
            const float fA = (SA.x + SA.y) + xp[tt].x;
            const float fB = (SB.x + SB.y) + xp[tt].y;
            hh.x = fast_tanh(fA);
            hh.y = fast_tanh(fB);

            *(v2f*)&hb[tt & 1][c0] = hh;                      // state (LDS)
            *(v2f*)(xbase + (long)(c * CH + tt) * HH + c0) = hh; // output (global,
                                                              // never waited on)
            asm volatile("s_waitcnt lgkmcnt(0)" ::: "memory"); // h visible to wave
        }
        if (c + 1 < NC) {
#pragma unroll
            for (int t = 0; t < 16; ++t) xp[t] = nxt[t];
        }
    }

    // final hidden state straight from registers
    *(v2f*)(out + (long)BB * SS * HH + b * HH + c0) = hh;
}

extern "C" void kernel_launch(void* const* d_in, const int* in_sizes, int n_in,
                              void* d_out, int out_size, void* d_ws, size_t ws_size,
                              hipStream_t stream) {
    const float* x    = (const float*)d_in[0];
    const float* W    = (const float*)d_in[1];
    const float* bias = (const float*)d_in[2];
    float* out = (float*)d_out;

    xproj_kernel<<<dim3((BB * SS) / 128), dim3(256), 0, stream>>>(x, W, bias, out);
    rnn_kernel<<<dim3(BB), dim3(64), 0, stream>>>(W, out);
}

// Round 8
// 788.707 us; speedup vs baseline: 3.8393x; 3.8393x over previous
//
#include <hip/hip_runtime.h>

#define BB 64
#define SS 2048
#define DD 128
#define HH 128

typedef float v2f __attribute__((ext_vector_type(2)));

// packed dual-fp32 FMA: acc.{lo,hi} += a.{lo,hi} * b.{lo,hi}
#define PKFMA(acc, a, b) \
    asm("v_pk_fma_f32 %0, %1, %2, %0" : "+v"(acc) : "v"(a), "v"(b))

// Keep-alive: force VALUE to live in a VGPR here; the asm result is opaque so
// the compiler cannot sink/remat the load that produced it into later code.
#define PIN(x) asm volatile("" : "+v"(x))

__device__ __forceinline__ float fast_tanh(float x) {
    // tanh(x) = 1 - 2/(e^{2x}+1); exact at +-inf, ~1e-6 rel err
    float e = __expf(2.0f * x);
    return 1.0f - __fdividef(2.0f, e + 1.0f);
}

// quad-local butterfly ALLreduce (lanes 4g..4g+3) via DPP quad_perm — VALU
// only; after both stages every lane of the quad holds the full sum.
__device__ __forceinline__ float quad_allreduce(float v) {
    int a = __builtin_amdgcn_update_dpp(0, __float_as_int(v), 0xB1, 0xF, 0xF, true); // [1,0,3,2] xor1
    v += __int_as_float(a);
    int c = __builtin_amdgcn_update_dpp(0, __float_as_int(v), 0x4E, 0xF, 0xF, true); // [2,3,0,1] xor2
    v += __int_as_float(c);
    return v;
}

// Raw workgroup barrier: LDS-drain only (no vmcnt(0) — chunk-boundary global
// ops may stay in flight across step barriers).
__device__ __forceinline__ void lds_sync() {
    asm volatile("s_waitcnt lgkmcnt(0)" ::: "memory");
    __builtin_amdgcn_s_barrier();
    asm volatile("" ::: "memory");
    __builtin_amdgcn_sched_barrier(0);
}

// ---------------------------------------------------------------------------
// Kernel 1: xproj = x @ Wx + b  (register-tiled fp32 GEMM) — unchanged (~45us)
// ---------------------------------------------------------------------------
__global__ __launch_bounds__(256, 2)
void xproj_kernel(const float* __restrict__ x, const float* __restrict__ W,
                  const float* __restrict__ bias, float* __restrict__ out) {
    __shared__ __align__(16) float4 wxs[64 * 32];   // Wx half: [64 k][128 j]
    __shared__ __align__(16) float4 xsw[128 * 16];  // x half:  [128 r][64 k], swizzled
    const int tid = threadIdx.x;
    const int tx  = tid & 15;
    const int ty  = tid >> 4;
    const long row0 = (long)blockIdx.x * 128;

    float acc[8][8];
#pragma unroll
    for (int i = 0; i < 8; ++i)
#pragma unroll
        for (int j = 0; j < 8; ++j) acc[i][j] = 0.f;

    for (int kh = 0; kh < 2; ++kh) {
        {
            const float4* wg = (const float4*)(W + kh * 64 * HH);
#pragma unroll
            for (int i = 0; i < 8; ++i) wxs[tid + i * 256] = wg[tid + i * 256];
        }
        {
#pragma unroll
            for (int i = 0; i < 8; ++i) {
                const int g  = tid + i * 256;
                const int r  = g >> 4;
                const int k4 = g & 15;
                const float4 v = ((const float4*)(x + (row0 + r) * DD + kh * 64))[k4];
                xsw[r * 16 + (k4 ^ ((r >> 3) & 7))] = v;
            }
        }
        __syncthreads();

        for (int k4 = 0; k4 < 16; ++k4) {
            float4 xa[8];
#pragma unroll
            for (int i = 0; i < 8; ++i)
                xa[i] = xsw[(ty * 8 + i) * 16 + (k4 ^ (ty & 7))];
            float4 wa[4][2];
#pragma unroll
            for (int kk = 0; kk < 4; ++kk) {
                wa[kk][0] = wxs[(k4 * 4 + kk) * 32 + tx * 2];
                wa[kk][1] = wxs[(k4 * 4 + kk) * 32 + tx * 2 + 1];
            }
#pragma unroll
            for (int i = 0; i < 8; ++i) {
#pragma unroll
                for (int kk = 0; kk < 4; ++kk) {
                    const float xv = (kk == 0) ? xa[i].x : (kk == 1) ? xa[i].y
                                   : (kk == 2) ? xa[i].z : xa[i].w;
                    acc[i][0] = fmaf(xv, wa[kk][0].x, acc[i][0]);
                    acc[i][1] = fmaf(xv, wa[kk][0].y, acc[i][1]);
                    acc[i][2] = fmaf(xv, wa[kk][0].z, acc[i][2]);
                    acc[i][3] = fmaf(xv, wa[kk][0].w, acc[i][3]);
                    acc[i][4] = fmaf(xv, wa[kk][1].x, acc[i][4]);
                    acc[i][5] = fmaf(xv, wa[kk][1].y, acc[i][5]);
                    acc[i][6] = fmaf(xv, wa[kk][1].z, acc[i][6]);
                    acc[i][7] = fmaf(xv, wa[kk][1].w, acc[i][7]);
                }
            }
        }
        __syncthreads();
    }

    const float4 b0 = ((const float4*)bias)[tx * 2];
    const float4 b1 = ((const float4*)bias)[tx * 2 + 1];
#pragma unroll
    for (int i = 0; i < 8; ++i) {
        const float4 o0 = make_float4(acc[i][0] + b0.x, acc[i][1] + b0.y,
                                      acc[i][2] + b0.z, acc[i][3] + b0.w);
        const float4 o1 = make_float4(acc[i][4] + b1.x, acc[i][5] + b1.y,
                                      acc[i][6] + b1.z, acc[i][7] + b1.w);
        float4* og = (float4*)(out + (row0 + ty * 8 + i) * HH);
        og[tx * 2]     = o0;
        og[tx * 2 + 1] = o1;
    }
}

// ---------------------------------------------------------------------------
// Kernel 2: recurrence v7 — R6 structure (64 blocks x 256 thr, 4 waves,
// J=2 cols/lane, k-split 4) + two fixes:
//  (a) whA/whB/xpc PINNED in VGPRs (asm keep-alive) — R1-R6 all had
//      VGPR_Count < array size: compiler was sinking Wh loads into the
//      step loop (per-step L2 reloads). Tell: VGPR_Count should be ~90-110.
//  (b) raw s_barrier + lgkmcnt(0) only — no vmcnt(0) drain at step barriers;
//      chunk-boundary flush/loads overlap the next steps.
// ---------------------------------------------------------------------------
__global__ __launch_bounds__(256, 1)
void rnn_kernel(const float* __restrict__ W, float* __restrict__ out) {
    const int CH = 16;
    const int NC = SS / CH;

    __shared__ __align__(16) float hos[CH * HH];   // h out-chunk (8KB)
    __shared__ __align__(16) float hb[2][HH];      // double-buffered state

    const int b    = blockIdx.x;
    const int tid  = threadIdx.x;
    const int w    = tid >> 6;
    const int lane = tid & 63;
    const int s    = lane & 3;      // k-slice: k in [32s, 32s+32)
    const int jj   = lane >> 2;     // 0..15
    const int j0   = w * 32 + 2 * jj;   // column pair (j0, j0+1)

    // Wh fragments, paired along K, quad-staggered to match read order
    v2f whA[16], whB[16];
#pragma unroll
    for (int m = 0; m < 16; ++m) {
        const int r = m >> 1, u = (m & 1) * 2;
        const int k = 32 * s + (((r + 2 * s) & 7) << 2) + u;
        const float* w0 = W + (long)(DD + k) * HH;
        const float* w1 = W + (long)(DD + k + 1) * HH;
        v2f a; a.x = w0[j0];     a.y = w1[j0];     whA[m] = a;
        v2f bb; bb.x = w0[j0 + 1]; bb.y = w1[j0 + 1]; whB[m] = bb;
    }
#pragma unroll
    for (int m = 0; m < 16; ++m) { PIN(whA[m]); PIN(whB[m]); }

    float* const xbase = out + (long)b * SS * HH;

    if (tid < 128) { hb[0][tid] = 0.f; hb[1][tid] = 0.f; }

    // xpc: this thread OWNS steps tt = 4s..4s+3 of the chunk, cols (j0,j0+1)
    v2f xpc[4];
    {
        const float* g = xbase + (4 * s) * HH + j0;
#pragma unroll
        for (int i = 0; i < 4; ++i) { xpc[i] = *(const v2f*)(g + i * HH); PIN(xpc[i]); }
    }
    lds_sync();

    for (int c = 0; c < NC; ++c) {
#pragma unroll
        for (int tt = 0; tt < CH; ++tt) {
            const int t = c * CH + tt;
            const float4* hv = (const float4*)hb[(t + 1) & 1];

            v2f A0 = {0.f, 0.f}, A1 = {0.f, 0.f};
            v2f B0 = {0.f, 0.f}, B1 = {0.f, 0.f};
#pragma unroll
            for (int r = 0; r < 8; ++r) {
                const float4 h4 = hv[8 * s + ((r + 2 * s) & 7)]; // staggered, 0-conflict
                v2f hlo; hlo.x = h4.x; hlo.y = h4.y;
                v2f hhi; hhi.x = h4.z; hhi.y = h4.w;
                PKFMA(A0, hlo, whA[2 * r]);
                PKFMA(A1, hhi, whA[2 * r + 1]);
                PKFMA(B0, hlo, whB[2 * r]);
                PKFMA(B1, hhi, whB[2 * r + 1]);
            }
            const v2f SA = A0 + A1;            // v_pk_add
            const v2f SB = B0 + B1;
            float fA = SA.x + SA.y;
            float fB = SB.x + SB.y;
            // owner lane folds xproj in BEFORE the allreduce (distributes free)
            const bool own = (s == (tt >> 2));
            fA += own ? xpc[tt & 3].x : 0.f;
            fB += own ? xpc[tt & 3].y : 0.f;
            fA = quad_allreduce(fA);
            fB = quad_allreduce(fB);

            const float hx = (s < 2) ? fA : fB;
            const float h  = fast_tanh(hx);     // all 64 lanes useful
            const int col  = j0 + (s >> 1);
            if ((s & 1) == 0) hb[t & 1][col] = h;        // state (s=0,2)
            else              hos[tt * HH + col] = h;    // output (s=1,3)
            lds_sync();
        }

        // flush h chunk to global (overwrites consumed xproj rows in place)
        {
            float4* hg = (float4*)(xbase + c * CH * HH);
            const float4* hl = (const float4*)hos;
            hg[tid]       = hl[tid];
            hg[tid + 256] = hl[tid + 256];
        }
        // load next chunk's xproj into registers (rows disjoint from flush)
        if (c + 1 < NC) {
            const float* g = xbase + (c + 1) * CH * HH + (4 * s) * HH + j0;
#pragma unroll
            for (int i = 0; i < 4; ++i) { xpc[i] = *(const v2f*)(g + i * HH); PIN(xpc[i]); }
        }
        lds_sync();   // protects hos reuse (flush-read done before next writes)
    }

    // final hidden state
    if (tid < 128) {
        out[(long)BB * SS * HH + b * HH + tid] = hb[1][tid];
    }
}

extern "C" void kernel_launch(void* const* d_in, const int* in_sizes, int n_in,
                              void* d_out, int out_size, void* d_ws, size_t ws_size,
                              hipStream_t stream) {
    const float* x    = (const float*)d_in[0];
    const float* W    = (const float*)d_in[1];
    const float* bias = (const float*)d_in[2];
    float* out = (float*)d_out;

    xproj_kernel<<<dim3((BB * SS) / 128), dim3(256), 0, stream>>>(x, W, bias, out);
    rnn_kernel<<<dim3(BB), dim3(256), 0, stream>>>(W, out);
}

// Round 10
// 733.403 us; speedup vs baseline: 4.1289x; 1.0754x over previous
//
#include <hip/hip_runtime.h>

#define BB 64
#define SS 2048
#define DD 128
#define HH 128

typedef float v2f __attribute__((ext_vector_type(2)));

// VOP3P packed-f32 FMA, all operands are VGPR PAIRS.
// PKBLO: both result lanes use the LOW word of src0 (h even):
//   acc.lo += h.lo*w.lo ; acc.hi += h.lo*w.hi
#define PKBLO(acc, hp, w) \
    asm("v_pk_fma_f32 %0, %1, %2, %0 op_sel_hi:[0,1,1]" \
        : "+v"(acc) : "v"(hp), "v"(w))
// PKBHI: both result lanes use the HIGH word of src0 (h odd):
#define PKBHI(acc, hp, w) \
    asm("v_pk_fma_f32 %0, %1, %2, %0 op_sel:[1,0,0] op_sel_hi:[1,1,1]" \
        : "+v"(acc) : "v"(hp), "v"(w))

// Opaque volatile load: cannot be sunk/remat'd into the loop — the result
// MUST stay register-resident for its whole live range.
#define LDW(var, r, u) { \
    const float* _p = Whp + (long)(32 * s + kr##r * 4 + (u)) * HH + j0; \
    asm volatile("global_load_dwordx2 %0, %1, off" : "=&v"(var) : "v"(_p)); }

__device__ __forceinline__ float fast_tanh(float x) {
    // tanh(x) = 1 - 2/(e^{2x}+1); exact at +-inf, ~1e-6 rel err
    float e = __expf(2.0f * x);
    return 1.0f - __fdividef(2.0f, e + 1.0f);
}

// quad-local butterfly ALLreduce (lanes 4g..4g+3) via DPP quad_perm — VALU only
__device__ __forceinline__ float quad_allreduce(float v) {
    int a = __builtin_amdgcn_update_dpp(0, __float_as_int(v), 0xB1, 0xF, 0xF, true); // xor1
    v += __int_as_float(a);
    int c = __builtin_amdgcn_update_dpp(0, __float_as_int(v), 0x4E, 0xF, 0xF, true); // xor2
    v += __int_as_float(c);
    return v;
}

// LDS-only workgroup barrier: NO vmcnt drain (global ops stay in flight).
__device__ __forceinline__ void wg_sync_lds() {
    asm volatile("s_waitcnt lgkmcnt(0)\n\ts_barrier" ::: "memory");
}

// ---------------------------------------------------------------------------
// Kernel 1: xproj = x @ Wx + b  (register-tiled fp32 GEMM) — unchanged (~45us)
// ---------------------------------------------------------------------------
__global__ __launch_bounds__(256, 2)
void xproj_kernel(const float* __restrict__ x, const float* __restrict__ W,
                  const float* __restrict__ bias, float* __restrict__ out) {
    __shared__ __align__(16) float4 wxs[64 * 32];   // Wx half: [64 k][128 j]
    __shared__ __align__(16) float4 xsw[128 * 16];  // x half:  [128 r][64 k], swizzled
    const int tid = threadIdx.x;
    const int tx  = tid & 15;
    const int ty  = tid >> 4;
    const long row0 = (long)blockIdx.x * 128;

    float acc[8][8];
#pragma unroll
    for (int i = 0; i < 8; ++i)
#pragma unroll
        for (int j = 0; j < 8; ++j) acc[i][j] = 0.f;

    for (int kh = 0; kh < 2; ++kh) {
        {
            const float4* wg = (const float4*)(W + kh * 64 * HH);
#pragma unroll
            for (int i = 0; i < 8; ++i) wxs[tid + i * 256] = wg[tid + i * 256];
        }
        {
#pragma unroll
            for (int i = 0; i < 8; ++i) {
                const int g  = tid + i * 256;
                const int r  = g >> 4;
                const int k4 = g & 15;
                const float4 v = ((const float4*)(x + (row0 + r) * DD + kh * 64))[k4];
                xsw[r * 16 + (k4 ^ ((r >> 3) & 7))] = v;
            }
        }
        __syncthreads();

        for (int k4 = 0; k4 < 16; ++k4) {
            float4 xa[8];
#pragma unroll
            for (int i = 0; i < 8; ++i)
                xa[i] = xsw[(ty * 8 + i) * 16 + (k4 ^ (ty & 7))];
            float4 wa[4][2];
#pragma unroll
            for (int kk = 0; kk < 4; ++kk) {
                wa[kk][0] = wxs[(k4 * 4 + kk) * 32 + tx * 2];
                wa[kk][1] = wxs[(k4 * 4 + kk) * 32 + tx * 2 + 1];
            }
#pragma unroll
            for (int i = 0; i < 8; ++i) {
#pragma unroll
                for (int kk = 0; kk < 4; ++kk) {
                    const float xv = (kk == 0) ? xa[i].x : (kk == 1) ? xa[i].y
                                   : (kk == 2) ? xa[i].z : xa[i].w;
                    acc[i][0] = fmaf(xv, wa[kk][0].x, acc[i][0]);
                    acc[i][1] = fmaf(xv, wa[kk][0].y, acc[i][1]);
                    acc[i][2] = fmaf(xv, wa[kk][0].z, acc[i][2]);
                    acc[i][3] = fmaf(xv, wa[kk][0].w, acc[i][3]);
                    acc[i][4] = fmaf(xv, wa[kk][1].x, acc[i][4]);
                    acc[i][5] = fmaf(xv, wa[kk][1].y, acc[i][5]);
                    acc[i][6] = fmaf(xv, wa[kk][1].z, acc[i][6]);
                    acc[i][7] = fmaf(xv, wa[kk][1].w, acc[i][7]);
                }
            }
        }
        __syncthreads();
    }

    const float4 b0 = ((const float4*)bias)[tx * 2];
    const float4 b1 = ((const float4*)bias)[tx * 2 + 1];
#pragma unroll
    for (int i = 0; i < 8; ++i) {
        const float4 o0 = make_float4(acc[i][0] + b0.x, acc[i][1] + b0.y,
                                      acc[i][2] + b0.z, acc[i][3] + b0.w);
        const float4 o1 = make_float4(acc[i][4] + b1.x, acc[i][5] + b1.y,
                                      acc[i][6] + b1.z, acc[i][7] + b1.w);
        float4* og = (float4*)(out + (row0 + ty * 8 + i) * HH);
        og[tx * 2]     = o0;
        og[tx * 2 + 1] = o1;
    }
}

// ---------------------------------------------------------------------------
// Kernel 2: recurrence v8b — R6 geometry (64 blk x 256 thr, 4 waves, J=2
// cols, k-split 4) with Wh FORCED register-resident:
//  - 32 named v2f loaded by asm volatile global_load_dwordx2 (unsinkable);
//    each = (Wh[k][j0], Wh[k][j0+1]) column pair
//  - v_pk_fma_f32 with op_sel word-broadcast of the h pair (VOP3P pairs)
//  - barrier = lgkmcnt(0)+s_barrier only; h stored straight to global per
//    step (never waited on); xproj prefetched TWO chunks ahead; LDS = 1KB
// ---------------------------------------------------------------------------
__global__ __launch_bounds__(256, 1)
void rnn_kernel(const float* __restrict__ W, float* __restrict__ out) {
    const int CH = 16;
    const int NC = SS / CH;   // 128

    __shared__ __align__(16) float hb[2][HH];      // double-buffered state (1KB)

    const int b    = blockIdx.x;
    const int tid  = threadIdx.x;
    const int w    = tid >> 6;
    const int lane = tid & 63;
    const int s    = lane & 3;          // k-slice: k in [32s, 32s+32)
    const int jj   = lane >> 2;         // 0..15
    const int j0   = w * 32 + 2 * jj;   // column pair (j0, j0+1)

    // per-lane staggered k-groups (bank-conflict-free h reads, proven 0 in R3-R8)
    const int kr0 = (0 + 2 * s) & 7, kr1 = (1 + 2 * s) & 7;
    const int kr2 = (2 + 2 * s) & 7, kr3 = (3 + 2 * s) & 7;
    const int kr4 = (4 + 2 * s) & 7, kr5 = (5 + 2 * s) & 7;
    const int kr6 = (6 + 2 * s) & 7, kr7 = (7 + 2 * s) & 7;

    const float* Whp = W + (long)DD * HH;

    // 32 named v2f = 64 VGPRs of Wh, loaded via opaque asm (CANNOT be sunk)
    v2f w00, w01, w02, w03, w10, w11, w12, w13;
    v2f w20, w21, w22, w23, w30, w31, w32, w33;
    v2f w40, w41, w42, w43, w50, w51, w52, w53;
    v2f w60, w61, w62, w63, w70, w71, w72, w73;
    LDW(w00,0,0) LDW(w01,0,1) LDW(w02,0,2) LDW(w03,0,3)
    LDW(w10,1,0) LDW(w11,1,1) LDW(w12,1,2) LDW(w13,1,3)
    LDW(w20,2,0) LDW(w21,2,1) LDW(w22,2,2) LDW(w23,2,3)
    LDW(w30,3,0) LDW(w31,3,1) LDW(w32,3,2) LDW(w33,3,3)
    LDW(w40,4,0) LDW(w41,4,1) LDW(w42,4,2) LDW(w43,4,3)
    LDW(w50,5,0) LDW(w51,5,1) LDW(w52,5,2) LDW(w53,5,3)
    LDW(w60,6,0) LDW(w61,6,1) LDW(w62,6,2) LDW(w63,6,3)
    LDW(w70,7,0) LDW(w71,7,1) LDW(w72,7,2) LDW(w73,7,3)

    float* const xbase = out + (long)b * SS * HH;

    if (tid < 128) { hb[0][tid] = 0.f; hb[1][tid] = 0.f; }

    // xproj: thread owns steps tt=4s..4s+3 of each chunk, cols (j0,j0+1).
    // Double prefetch (chunks c and c+1 in regs) -> 16-step margin before the
    // in-place overwrite of any row we have in flight.
    v2f xpc[4], nxt[4];
    {
        const float* g0 = xbase + (4 * s) * HH + j0;
        const float* g1 = xbase + (CH + 4 * s) * HH + j0;
#pragma unroll
        for (int i = 0; i < 4; ++i) { xpc[i] = *(const v2f*)(g0 + i * HH);
                                      nxt[i] = *(const v2f*)(g1 + i * HH); }
    }
    // all Wh + initial xproj loads complete before anyone passes the barrier
    asm volatile("s_waitcnt vmcnt(0)" ::: "memory");
    wg_sync_lds();

    for (int c = 0; c < NC; ++c) {
#pragma unroll
        for (int tt = 0; tt < CH; ++tt) {
            const int t = c * CH + tt;
            const float4* hv = (const float4*)hb[(t + 1) & 1];

            v2f P0 = {0.f, 0.f}, P1 = {0.f, 0.f};
            v2f P2 = {0.f, 0.f}, P3 = {0.f, 0.f};
#define STEP_R(r) { \
            const float4 h4 = hv[8 * s + kr##r]; \
            v2f hlo; hlo.x = h4.x; hlo.y = h4.y; \
            v2f hhi; hhi.x = h4.z; hhi.y = h4.w; \
            PKBLO(P0, hlo, w##r##0); \
            PKBHI(P1, hlo, w##r##1); \
            PKBLO(P2, hhi, w##r##2); \
            PKBHI(P3, hhi, w##r##3); }
            STEP_R(0) STEP_R(1) STEP_R(2) STEP_R(3)
            STEP_R(4) STEP_R(5) STEP_R(6) STEP_R(7)
#undef STEP_R
            const v2f P = (P0 + P1) + (P2 + P3);
            float fA = P.x, fB = P.y;
            // owner lane folds xproj BEFORE the allreduce (distributed free)
            const bool own = (s == (tt >> 2));
            fA += own ? xpc[tt & 3].x : 0.f;
            fB += own ? xpc[tt & 3].y : 0.f;
            fA = quad_allreduce(fA);
            fB = quad_allreduce(fB);

            const float h = fast_tanh((s < 2) ? fA : fB);
            const int col = j0 + (s >> 1);
            if ((s & 1) == 0) hb[t & 1][col] = h;          // state  (s=0,2)
            else              xbase[(long)t * HH + col] = h; // output (s=1,3),
                                                           // fire-and-forget
            wg_sync_lds();   // lgkm-only: stores/prefetch stay in flight
        }
        // rotate prefetch: xpc <- nxt, nxt <- chunk c+2 (16-step margin)
        if (c + 1 < NC) {
#pragma unroll
            for (int i = 0; i < 4; ++i) xpc[i] = nxt[i];
            if (c + 2 < NC) {
                const float* g = xbase + ((long)(c + 2) * CH + 4 * s) * HH + j0;
#pragma unroll
                for (int i = 0; i < 4; ++i) nxt[i] = *(const v2f*)(g + i * HH);
            }
        }
    }

    // final hidden state
    if (tid < 128) {
        out[(long)BB * SS * HH + b * HH + tid] = hb[1][tid];
    }
}

extern "C" void kernel_launch(void* const* d_in, const int* in_sizes, int n_in,
                              void* d_out, int out_size, void* d_ws, size_t ws_size,
                              hipStream_t stream) {
    const float* x    = (const float*)d_in[0];
    const float* W    = (const float*)d_in[1];
    const float* bias = (const float*)d_in[2];
    float* out = (float*)d_out;

    xproj_kernel<<<dim3((BB * SS) / 128), dim3(256), 0, stream>>>(x, W, bias, out);
    rnn_kernel<<<dim3(BB), dim3(256), 0, stream>>>(W, out);
}